// Round 1
// baseline (603.974 us; speedup 1.0000x reference)
//
#include <hip/hip_runtime.h>
#include <math.h>

#define NNODES 50000
#define NEDGES 640000
#define INSZ 512
#define HID 128

// ---------------- degree kernels ----------------
__global__ __launch_bounds__(256) void init_deg_kernel(float* __restrict__ deg) {
    int i = blockIdx.x * blockDim.x + threadIdx.x;
    if (i < NNODES) deg[i] = 1.0f;   // self-loop contributes 1
}

__global__ __launch_bounds__(256) void count_deg_kernel(const int* __restrict__ col,
                                                        float* __restrict__ deg) {
    int e = blockIdx.x * blockDim.x + threadIdx.x;
    if (e < NEDGES) atomicAdd(&deg[col[e]], 1.0f);
}

__global__ __launch_bounds__(256) void dinv_kernel(float* __restrict__ deg) {
    int i = blockIdx.x * blockDim.x + threadIdx.x;
    if (i < NNODES) deg[i] = rsqrtf(deg[i]);   // deg >= 1 always (self-loop)
}

// ---------------- encoder: h = relu(x @ W_enc + b_enc) ----------------
// 16 nodes per 256-thread block. x rows staged in LDS (32 KB).
// thread = (j in 0..127, g in 0..1); g handles nodes g*8..g*8+7.
__global__ __launch_bounds__(256) void encoder_kernel(const float* __restrict__ x,
                                                      const float* __restrict__ W,
                                                      const float* __restrict__ b,
                                                      float* __restrict__ h) {
    __shared__ float xs[16 * INSZ];            // 32 KB
    const int n0 = blockIdx.x * 16;
    const float4* src = (const float4*)(x + (size_t)n0 * INSZ);
    float4* dst = (float4*)xs;
#pragma unroll
    for (int s = 0; s < 8; ++s)
        dst[threadIdx.x + 256 * s] = src[threadIdx.x + 256 * s];
    __syncthreads();

    const int j = threadIdx.x & 127;
    const int g = threadIdx.x >> 7;
    const float bj = b[j];
    float acc[8];
#pragma unroll
    for (int m = 0; m < 8; ++m) acc[m] = bj;

    const float* xsg = xs + (g * 8) * INSZ;
#pragma unroll 4
    for (int k = 0; k < INSZ; ++k) {
        const float w = W[k * HID + j];
#pragma unroll
        for (int m = 0; m < 8; ++m)
            acc[m] = fmaf(xsg[m * INSZ + k], w, acc[m]);
    }
#pragma unroll
    for (int m = 0; m < 8; ++m)
        h[(size_t)(n0 + g * 8 + m) * HID + j] = fmaxf(acc[m], 0.0f);
}

// ---------------- aggregation: agg[col] += dinv[row]*dinv[col]*h[row] ----------------
// One thread per (edge, k). Edges [0,NEDGES) are graph edges, [NEDGES, NEDGES+NNODES)
// are self-loops.
__global__ __launch_bounds__(256) void aggregate_kernel(const int* __restrict__ rows,
                                                        const int* __restrict__ cols,
                                                        const float* __restrict__ dinv,
                                                        const float* __restrict__ h,
                                                        float* __restrict__ agg) {
    const long long t = (long long)blockIdx.x * 256 + threadIdx.x;
    const int e = (int)(t >> 7);
    const int k = (int)(t & 127);
    if (e >= NEDGES + NNODES) return;
    int r, c;
    if (e < NEDGES) { r = rows[e]; c = cols[e]; }
    else            { r = c = e - NEDGES; }
    const float norm = dinv[r] * dinv[c];
    atomicAdd(&agg[(size_t)c * HID + k], norm * h[(size_t)r * HID + k]);
}

// ---------------- decoder: out = sigmoid((agg + gcn_bias) @ W_dec + b_dec) ----------------
// 8 nodes per 256-thread block; thread handles columns j0 and j0+256 for all 8 nodes.
__global__ __launch_bounds__(256) void decoder_kernel(const float* __restrict__ agg,
                                                      const float* __restrict__ gb,
                                                      const float* __restrict__ W,
                                                      const float* __restrict__ b,
                                                      float* __restrict__ out) {
    __shared__ float as[8 * HID];              // 4 KB
    const int n0 = blockIdx.x * 8;
    const float4* src = (const float4*)(agg + (size_t)n0 * HID);
    float4* dst = (float4*)as;
    dst[threadIdx.x] = src[threadIdx.x];       // 1024 floats = 256 float4
    __syncthreads();
#pragma unroll
    for (int s = 0; s < 4; ++s) {
        int idx = threadIdx.x + 256 * s;
        as[idx] += gb[idx & 127];
    }
    __syncthreads();

    const int j0 = threadIdx.x;
    float acc0[8], acc1[8];
    const float b0 = b[j0], b1 = b[j0 + 256];
#pragma unroll
    for (int m = 0; m < 8; ++m) { acc0[m] = b0; acc1[m] = b1; }

#pragma unroll 4
    for (int k = 0; k < HID; ++k) {
        const float w0 = W[k * INSZ + j0];
        const float w1 = W[k * INSZ + j0 + 256];
#pragma unroll
        for (int m = 0; m < 8; ++m) {
            const float a = as[m * HID + k];
            acc0[m] = fmaf(a, w0, acc0[m]);
            acc1[m] = fmaf(a, w1, acc1[m]);
        }
    }
#pragma unroll
    for (int m = 0; m < 8; ++m) {
        out[(size_t)(n0 + m) * INSZ + j0]       = 1.0f / (1.0f + __expf(-acc0[m]));
        out[(size_t)(n0 + m) * INSZ + j0 + 256] = 1.0f / (1.0f + __expf(-acc1[m]));
    }
}

extern "C" void kernel_launch(void* const* d_in, const int* in_sizes, int n_in,
                              void* d_out, int out_size, void* d_ws, size_t ws_size,
                              hipStream_t stream) {
    const float* x        = (const float*)d_in[0];
    const float* W_enc    = (const float*)d_in[1];
    const float* b_enc    = (const float*)d_in[2];
    const float* W_dec    = (const float*)d_in[3];
    const float* b_dec    = (const float*)d_in[4];
    const float* gcn_bias = (const float*)d_in[5];
    const int*   edge     = (const int*)d_in[6];
    const int*   erow = edge;            // edge_index[0] = source
    const int*   ecol = edge + NEDGES;   // edge_index[1] = target

    float* out = (float*)d_out;
    float* agg = (float*)d_ws;                         // NNODES*HID floats (25.6 MB)
    float* deg = agg + (size_t)NNODES * HID;           // NNODES floats
    float* h   = out;                                  // reuse d_out front as scratch
                                                       // (decoder never reads h)

    hipMemsetAsync(agg, 0, (size_t)NNODES * HID * sizeof(float), stream);
    init_deg_kernel<<<(NNODES + 255) / 256, 256, 0, stream>>>(deg);
    count_deg_kernel<<<(NEDGES + 255) / 256, 256, 0, stream>>>(ecol, deg);
    encoder_kernel<<<NNODES / 16, 256, 0, stream>>>(x, W_enc, b_enc, h);
    dinv_kernel<<<(NNODES + 255) / 256, 256, 0, stream>>>(deg);
    const long long aggthreads = (long long)(NEDGES + NNODES) * HID;
    aggregate_kernel<<<(int)((aggthreads + 255) / 256), 256, 0, stream>>>(erow, ecol, deg, h, agg);
    decoder_kernel<<<NNODES / 8, 256, 0, stream>>>(agg, gcn_bias, W_dec, b_dec, out);
}

// Round 2
// 519.359 us; speedup vs baseline: 1.1629x; 1.1629x over previous
//
#include <hip/hip_runtime.h>
#include <math.h>

#define NNODES 50000
#define NEDGES 640000
#define INSZ 512
#define HID 128

// ---------------- CSR build ----------------
__global__ __launch_bounds__(256) void count_kernel(const int* __restrict__ col,
                                                    int* __restrict__ counts) {
    int e = blockIdx.x * blockDim.x + threadIdx.x;
    if (e < NEDGES) atomicAdd(&counts[col[e]], 1);
}

// Exclusive scan of counts[NNODES] -> starts[NNODES+1], also copies to cursor.
// Single block, 1024 threads, 49 elems/thread (1024*49 = 50176 >= 50000).
#define SCAN_CHUNK 49
__global__ __launch_bounds__(1024) void scan_kernel(const int* __restrict__ counts,
                                                    int* __restrict__ starts,
                                                    int* __restrict__ cursor) {
    __shared__ int psum[1024];
    const int t = threadIdx.x;
    const int base = t * SCAN_CHUNK;
    int s = 0;
    for (int i = 0; i < SCAN_CHUNK; ++i) {
        int idx = base + i;
        if (idx < NNODES) s += counts[idx];
    }
    psum[t] = s;
    __syncthreads();
    // Hillis-Steele inclusive scan over 1024 partials
    for (int off = 1; off < 1024; off <<= 1) {
        int v = (t >= off) ? psum[t - off] : 0;
        __syncthreads();
        psum[t] += v;
        __syncthreads();
    }
    int run = (t == 0) ? 0 : psum[t - 1];   // exclusive offset for this chunk
    for (int i = 0; i < SCAN_CHUNK; ++i) {
        int idx = base + i;
        if (idx < NNODES) {
            starts[idx] = run;
            cursor[idx] = run;
            run += counts[idx];
        }
    }
    if (t == 1023) starts[NNODES] = psum[1023];
}

__global__ __launch_bounds__(256) void scatter_kernel(const int* __restrict__ erow,
                                                      const int* __restrict__ ecol,
                                                      int* __restrict__ cursor,
                                                      int* __restrict__ csr_row) {
    int e = blockIdx.x * blockDim.x + threadIdx.x;
    if (e < NEDGES) {
        int pos = atomicAdd(&cursor[ecol[e]], 1);
        csr_row[pos] = erow[e];
    }
}

__global__ __launch_bounds__(256) void dinv_kernel(const int* __restrict__ counts,
                                                   float* __restrict__ dinv) {
    int i = blockIdx.x * blockDim.x + threadIdx.x;
    if (i < NNODES) dinv[i] = rsqrtf((float)counts[i] + 1.0f);  // +1 self-loop
}

// ---------------- encoder: h = relu(x @ W_enc + b_enc) ----------------
__global__ __launch_bounds__(256) void encoder_kernel(const float* __restrict__ x,
                                                      const float* __restrict__ W,
                                                      const float* __restrict__ b,
                                                      float* __restrict__ h) {
    __shared__ float xs[16 * INSZ];            // 32 KB
    const int n0 = blockIdx.x * 16;
    const float4* src = (const float4*)(x + (size_t)n0 * INSZ);
    float4* dst = (float4*)xs;
#pragma unroll
    for (int s = 0; s < 8; ++s)
        dst[threadIdx.x + 256 * s] = src[threadIdx.x + 256 * s];
    __syncthreads();

    const int j = threadIdx.x & 127;
    const int g = threadIdx.x >> 7;
    const float bj = b[j];
    float acc[8];
#pragma unroll
    for (int m = 0; m < 8; ++m) acc[m] = bj;

    const float* xsg = xs + (g * 8) * INSZ;
#pragma unroll 4
    for (int k = 0; k < INSZ; ++k) {
        const float w = W[k * HID + j];
#pragma unroll
        for (int m = 0; m < 8; ++m)
            acc[m] = fmaf(xsg[m * INSZ + k], w, acc[m]);
    }
#pragma unroll
    for (int m = 0; m < 8; ++m)
        h[(size_t)(n0 + g * 8 + m) * HID + j] = fmaxf(acc[m], 0.0f);
}

// ---------------- aggregation (CSR gather): one wave per target node ----------------
__global__ __launch_bounds__(256) void aggregate_csr_kernel(const int* __restrict__ starts,
                                                            const int* __restrict__ csr_row,
                                                            const float* __restrict__ dinv,
                                                            const float* __restrict__ h,
                                                            float* __restrict__ agg) {
    const int wid  = (blockIdx.x * 256 + threadIdx.x) >> 6;   // node id
    const int lane = threadIdx.x & 63;
    if (wid >= NNODES) return;
    const int c = wid;
    const float dc = dinv[c];
    const int s0 = starts[c], s1 = starts[c + 1];
    const float2* hp = (const float2*)h;

    float2 acc = hp[(size_t)c * 64 + lane];    // self-loop
    acc.x *= dc * dc;
    acc.y *= dc * dc;

    int i = s0;
    for (; i + 1 < s1; i += 2) {               // 2-way ILP on the gather
        int r0 = csr_row[i], r1 = csr_row[i + 1];
        float n0 = dinv[r0] * dc, n1 = dinv[r1] * dc;
        float2 h0 = hp[(size_t)r0 * 64 + lane];
        float2 h1 = hp[(size_t)r1 * 64 + lane];
        acc.x = fmaf(n0, h0.x, acc.x); acc.y = fmaf(n0, h0.y, acc.y);
        acc.x = fmaf(n1, h1.x, acc.x); acc.y = fmaf(n1, h1.y, acc.y);
    }
    if (i < s1) {
        int r = csr_row[i];
        float nrm = dinv[r] * dc;
        float2 hv = hp[(size_t)r * 64 + lane];
        acc.x = fmaf(nrm, hv.x, acc.x);
        acc.y = fmaf(nrm, hv.y, acc.y);
    }
    ((float2*)agg)[(size_t)c * 64 + lane] = acc;
}

// ---------------- decoder: out = sigmoid((agg + gcn_bias) @ W_dec + b_dec) ----------------
__global__ __launch_bounds__(256) void decoder_kernel(const float* __restrict__ agg,
                                                      const float* __restrict__ gb,
                                                      const float* __restrict__ W,
                                                      const float* __restrict__ b,
                                                      float* __restrict__ out) {
    __shared__ float as[8 * HID];              // 4 KB
    const int n0 = blockIdx.x * 8;
    const float4* src = (const float4*)(agg + (size_t)n0 * HID);
    float4* dst = (float4*)as;
    dst[threadIdx.x] = src[threadIdx.x];
    __syncthreads();
#pragma unroll
    for (int s = 0; s < 4; ++s) {
        int idx = threadIdx.x + 256 * s;
        as[idx] += gb[idx & 127];
    }
    __syncthreads();

    const int j0 = threadIdx.x;
    float acc0[8], acc1[8];
    const float b0 = b[j0], b1 = b[j0 + 256];
#pragma unroll
    for (int m = 0; m < 8; ++m) { acc0[m] = b0; acc1[m] = b1; }

#pragma unroll 4
    for (int k = 0; k < HID; ++k) {
        const float w0 = W[k * INSZ + j0];
        const float w1 = W[k * INSZ + j0 + 256];
#pragma unroll
        for (int m = 0; m < 8; ++m) {
            const float a = as[m * HID + k];
            acc0[m] = fmaf(a, w0, acc0[m]);
            acc1[m] = fmaf(a, w1, acc1[m]);
        }
    }
#pragma unroll
    for (int m = 0; m < 8; ++m) {
        out[(size_t)(n0 + m) * INSZ + j0]       = 1.0f / (1.0f + __expf(-acc0[m]));
        out[(size_t)(n0 + m) * INSZ + j0 + 256] = 1.0f / (1.0f + __expf(-acc1[m]));
    }
}

extern "C" void kernel_launch(void* const* d_in, const int* in_sizes, int n_in,
                              void* d_out, int out_size, void* d_ws, size_t ws_size,
                              hipStream_t stream) {
    const float* x        = (const float*)d_in[0];
    const float* W_enc    = (const float*)d_in[1];
    const float* b_enc    = (const float*)d_in[2];
    const float* W_dec    = (const float*)d_in[3];
    const float* b_dec    = (const float*)d_in[4];
    const float* gcn_bias = (const float*)d_in[5];
    const int*   edge     = (const int*)d_in[6];
    const int*   erow = edge;            // edge_index[0] = source
    const int*   ecol = edge + NEDGES;   // edge_index[1] = target

    float* out = (float*)d_out;
    // ws: agg (50000*128 f32) + dinv (50000 f32)  -> same footprint as round 1
    float* agg  = (float*)d_ws;
    float* dinv = agg + (size_t)NNODES * HID;
    // d_out tail as scratch (all dead before decoder writes d_out):
    //   h at [0, 6.4M) floats; then csr_row, starts, counts, cursor
    float* h        = out;
    int*   csr_row  = (int*)(out + (size_t)NNODES * HID);
    int*   starts   = csr_row + NEDGES;
    int*   counts   = starts + NNODES + 1;
    int*   cursor   = counts + NNODES;

    hipMemsetAsync(counts, 0, (size_t)NNODES * sizeof(int), stream);
    count_kernel<<<(NEDGES + 255) / 256, 256, 0, stream>>>(ecol, counts);
    scan_kernel<<<1, 1024, 0, stream>>>(counts, starts, cursor);
    dinv_kernel<<<(NNODES + 255) / 256, 256, 0, stream>>>(counts, dinv);
    scatter_kernel<<<(NEDGES + 255) / 256, 256, 0, stream>>>(erow, ecol, cursor, csr_row);
    encoder_kernel<<<NNODES / 16, 256, 0, stream>>>(x, W_enc, b_enc, h);
    aggregate_csr_kernel<<<(NNODES * 64 + 255) / 256, 256, 0, stream>>>(starts, csr_row, dinv, h, agg);
    decoder_kernel<<<NNODES / 8, 256, 0, stream>>>(agg, gcn_bias, W_dec, b_dec, out);
}

// Round 3
// 413.689 us; speedup vs baseline: 1.4600x; 1.2554x over previous
//
#include <hip/hip_runtime.h>
#include <math.h>

#define NNODES 50000
#define NEDGES 640000
#define INSZ 512
#define HID 128

typedef short s16x8 __attribute__((ext_vector_type(8)));
typedef float f32x4 __attribute__((ext_vector_type(4)));

static __device__ inline short f2bf(float f) {
    __bf16 b = (__bf16)f;                 // RNE, compiler emits cvt_pk where possible
    return __builtin_bit_cast(short, b);
}

// ---------------- weight prep: transpose + bf16 convert ----------------
__global__ __launch_bounds__(256) void prep_wenc(const float* __restrict__ W,
                                                 short* __restrict__ WT) {
    int t = blockIdx.x * 256 + threadIdx.x;      // 65536 total
    if (t < INSZ * HID) {
        int n = t & (HID - 1);                   // W is [k][n], n fastest
        int k = t >> 7;
        WT[n * INSZ + k] = f2bf(W[t]);           // WT is [n][k]
    }
}
__global__ __launch_bounds__(256) void prep_wdec(const float* __restrict__ W,
                                                 short* __restrict__ WT) {
    int t = blockIdx.x * 256 + threadIdx.x;      // 65536 total
    if (t < HID * INSZ) {
        int n = t & (INSZ - 1);                  // W is [k][n], n fastest
        int k = t >> 9;
        WT[n * HID + k] = f2bf(W[t]);            // WT is [n][k]
    }
}

// ---------------- CSR build ----------------
__global__ __launch_bounds__(256) void count_kernel(const int* __restrict__ col,
                                                    int* __restrict__ counts) {
    int e = blockIdx.x * blockDim.x + threadIdx.x;
    if (e < NEDGES) atomicAdd(&counts[col[e]], 1);
}

#define SCAN_CHUNK 49
__global__ __launch_bounds__(1024) void scan_kernel(const int* __restrict__ counts,
                                                    int* __restrict__ starts,
                                                    int* __restrict__ cursor) {
    __shared__ int psum[1024];
    const int t = threadIdx.x;
    const int base = t * SCAN_CHUNK;
    int s = 0;
    for (int i = 0; i < SCAN_CHUNK; ++i) {
        int idx = base + i;
        if (idx < NNODES) s += counts[idx];
    }
    psum[t] = s;
    __syncthreads();
    for (int off = 1; off < 1024; off <<= 1) {
        int v = (t >= off) ? psum[t - off] : 0;
        __syncthreads();
        psum[t] += v;
        __syncthreads();
    }
    int run = (t == 0) ? 0 : psum[t - 1];
    for (int i = 0; i < SCAN_CHUNK; ++i) {
        int idx = base + i;
        if (idx < NNODES) {
            starts[idx] = run;
            cursor[idx] = run;
            run += counts[idx];
        }
    }
    if (t == 1023) starts[NNODES] = psum[1023];
}

__global__ __launch_bounds__(256) void scatter_kernel(const int* __restrict__ erow,
                                                      const int* __restrict__ ecol,
                                                      int* __restrict__ cursor,
                                                      int* __restrict__ csr_row) {
    int e = blockIdx.x * blockDim.x + threadIdx.x;
    if (e < NEDGES) {
        int pos = atomicAdd(&cursor[ecol[e]], 1);
        csr_row[pos] = erow[e];
    }
}

__global__ __launch_bounds__(256) void dinv_kernel(const int* __restrict__ counts,
                                                   float* __restrict__ dinv) {
    int i = blockIdx.x * blockDim.x + threadIdx.x;
    if (i < NNODES) dinv[i] = rsqrtf((float)counts[i] + 1.0f);
}

// ---------------- encoder: h = relu(x @ W_enc + b_enc), MFMA bf16 ----------------
// 64 rows/block, 256 threads = 4 waves, wave w owns n-cols [32w, 32w+32).
__global__ __launch_bounds__(256) void encoder_mfma(const float* __restrict__ x,
                                                    const short* __restrict__ WT,
                                                    const float* __restrict__ b,
                                                    float* __restrict__ h) {
    const int lane = threadIdx.x & 63;
    const int wv   = threadIdx.x >> 6;
    const int r16  = lane & 15;
    const int kg   = lane >> 4;           // 0..3
    const int mbase = blockIdx.x * 64;
    const int nb    = wv * 32;

    int arow[4];
#pragma unroll
    for (int mt = 0; mt < 4; ++mt) {
        int rr = mbase + mt * 16 + r16;
        arow[mt] = rr < NNODES ? rr : NNODES - 1;
    }

    f32x4 acc[4][2] = {};
    for (int ks = 0; ks < 16; ++ks) {
        const int k0 = ks * 32 + kg * 8;
        s16x8 a[4], bb[2];
#pragma unroll
        for (int mt = 0; mt < 4; ++mt) {
            const float* p = x + (size_t)arow[mt] * INSZ + k0;
            float4 u = *(const float4*)p;
            float4 v = *(const float4*)(p + 4);
            a[mt][0] = f2bf(u.x); a[mt][1] = f2bf(u.y);
            a[mt][2] = f2bf(u.z); a[mt][3] = f2bf(u.w);
            a[mt][4] = f2bf(v.x); a[mt][5] = f2bf(v.y);
            a[mt][6] = f2bf(v.z); a[mt][7] = f2bf(v.w);
        }
#pragma unroll
        for (int nt = 0; nt < 2; ++nt)
            bb[nt] = *(const s16x8*)(WT + (size_t)(nb + nt * 16 + r16) * INSZ + k0);
#pragma unroll
        for (int mt = 0; mt < 4; ++mt)
#pragma unroll
            for (int nt = 0; nt < 2; ++nt)
                acc[mt][nt] = __builtin_amdgcn_mfma_f32_16x16x32_bf16(a[mt], bb[nt], acc[mt][nt], 0, 0, 0);
    }

    const int ro = kg * 4;                 // C/D: row = (lane>>4)*4 + reg
#pragma unroll
    for (int mt = 0; mt < 4; ++mt) {
        const int row0 = mbase + mt * 16 + ro;
#pragma unroll
        for (int nt = 0; nt < 2; ++nt) {
            const int col = nb + nt * 16 + r16;
            const float bj = b[col];
#pragma unroll
            for (int v = 0; v < 4; ++v) {
                int rr = row0 + v;
                if (rr < NNODES)
                    h[(size_t)rr * HID + col] = fmaxf(acc[mt][nt][v] + bj, 0.0f);
            }
        }
    }
}

// ---------------- aggregation (CSR gather): one wave per target node ----------------
__global__ __launch_bounds__(256) void aggregate_csr_kernel(const int* __restrict__ starts,
                                                            const int* __restrict__ csr_row,
                                                            const float* __restrict__ dinv,
                                                            const float* __restrict__ h,
                                                            float* __restrict__ agg) {
    const int wid  = (blockIdx.x * 256 + threadIdx.x) >> 6;
    const int lane = threadIdx.x & 63;
    if (wid >= NNODES) return;
    const int c = wid;
    const float dc = dinv[c];
    const int s0 = starts[c], s1 = starts[c + 1];
    const float2* hp = (const float2*)h;

    float2 acc = hp[(size_t)c * 64 + lane];
    acc.x *= dc * dc;
    acc.y *= dc * dc;

    int i = s0;
    for (; i + 1 < s1; i += 2) {
        int r0 = csr_row[i], r1 = csr_row[i + 1];
        float n0 = dinv[r0] * dc, n1 = dinv[r1] * dc;
        float2 h0 = hp[(size_t)r0 * 64 + lane];
        float2 h1 = hp[(size_t)r1 * 64 + lane];
        acc.x = fmaf(n0, h0.x, acc.x); acc.y = fmaf(n0, h0.y, acc.y);
        acc.x = fmaf(n1, h1.x, acc.x); acc.y = fmaf(n1, h1.y, acc.y);
    }
    if (i < s1) {
        int r = csr_row[i];
        float nrm = dinv[r] * dc;
        float2 hv = hp[(size_t)r * 64 + lane];
        acc.x = fmaf(nrm, hv.x, acc.x);
        acc.y = fmaf(nrm, hv.y, acc.y);
    }
    ((float2*)agg)[(size_t)c * 64 + lane] = acc;
}

// ---------------- decoder: out = sigmoid((agg+gb) @ W_dec + b_dec), MFMA bf16 -------
// 32 rows/block, 4 waves, wave w owns n-cols [128w, 128w+128) (8 n-tiles).
__global__ __launch_bounds__(256) void decoder_mfma(const float* __restrict__ agg,
                                                    const float* __restrict__ gb,
                                                    const short* __restrict__ WT,
                                                    const float* __restrict__ b,
                                                    float* __restrict__ out) {
    const int lane = threadIdx.x & 63;
    const int wv   = threadIdx.x >> 6;
    const int r16  = lane & 15;
    const int kg   = lane >> 4;
    const int mbase = blockIdx.x * 32;
    const int nb    = wv * 128;

    int arow[2];
#pragma unroll
    for (int mt = 0; mt < 2; ++mt) {
        int rr = mbase + mt * 16 + r16;
        arow[mt] = rr < NNODES ? rr : NNODES - 1;
    }

    f32x4 acc[2][8] = {};
#pragma unroll
    for (int ks = 0; ks < 4; ++ks) {
        const int k0 = ks * 32 + kg * 8;
        const float4 g0 = *(const float4*)(gb + k0);
        const float4 g1 = *(const float4*)(gb + k0 + 4);
        s16x8 a[2], bb[8];
#pragma unroll
        for (int mt = 0; mt < 2; ++mt) {
            const float* p = agg + (size_t)arow[mt] * HID + k0;
            float4 u = *(const float4*)p;
            float4 v = *(const float4*)(p + 4);
            a[mt][0] = f2bf(u.x + g0.x); a[mt][1] = f2bf(u.y + g0.y);
            a[mt][2] = f2bf(u.z + g0.z); a[mt][3] = f2bf(u.w + g0.w);
            a[mt][4] = f2bf(v.x + g1.x); a[mt][5] = f2bf(v.y + g1.y);
            a[mt][6] = f2bf(v.z + g1.z); a[mt][7] = f2bf(v.w + g1.w);
        }
#pragma unroll
        for (int nt = 0; nt < 8; ++nt)
            bb[nt] = *(const s16x8*)(WT + (size_t)(nb + nt * 16 + r16) * HID + k0);
#pragma unroll
        for (int mt = 0; mt < 2; ++mt)
#pragma unroll
            for (int nt = 0; nt < 8; ++nt)
                acc[mt][nt] = __builtin_amdgcn_mfma_f32_16x16x32_bf16(a[mt], bb[nt], acc[mt][nt], 0, 0, 0);
    }

    const int ro = kg * 4;
#pragma unroll
    for (int mt = 0; mt < 2; ++mt) {
        const int row0 = mbase + mt * 16 + ro;
#pragma unroll
        for (int nt = 0; nt < 8; ++nt) {
            const int col = nb + nt * 16 + r16;
            const float bj = b[col];
#pragma unroll
            for (int v = 0; v < 4; ++v) {
                int rr = row0 + v;
                if (rr < NNODES) {
                    float z = acc[mt][nt][v] + bj;
                    out[(size_t)rr * INSZ + col] = 1.0f / (1.0f + __expf(-z));
                }
            }
        }
    }
}

extern "C" void kernel_launch(void* const* d_in, const int* in_sizes, int n_in,
                              void* d_out, int out_size, void* d_ws, size_t ws_size,
                              hipStream_t stream) {
    const float* x        = (const float*)d_in[0];
    const float* W_enc    = (const float*)d_in[1];
    const float* b_enc    = (const float*)d_in[2];
    const float* W_dec    = (const float*)d_in[3];
    const float* b_dec    = (const float*)d_in[4];
    const float* gcn_bias = (const float*)d_in[5];
    const int*   edge     = (const int*)d_in[6];
    const int*   erow = edge;
    const int*   ecol = edge + NEDGES;

    float* out = (float*)d_out;
    // ws: agg (6.4M f32) + dinv (50K f32) + W_decT (65536 bf16)
    float* agg   = (float*)d_ws;
    float* dinv  = agg + (size_t)NNODES * HID;
    short* wdecT = (short*)(dinv + NNODES);
    // d_out tail scratch (dead before decoder writes d_out):
    float* h       = out;
    int*   csr_row = (int*)(out + (size_t)NNODES * HID);
    int*   starts  = csr_row + NEDGES;
    int*   counts  = starts + NNODES + 1;
    int*   cursor  = counts + NNODES;
    short* wencT   = (short*)(cursor + NNODES);

    hipMemsetAsync(counts, 0, (size_t)NNODES * sizeof(int), stream);
    prep_wenc<<<(INSZ * HID + 255) / 256, 256, 0, stream>>>(W_enc, wencT);
    prep_wdec<<<(HID * INSZ + 255) / 256, 256, 0, stream>>>(W_dec, wdecT);
    count_kernel<<<(NEDGES + 255) / 256, 256, 0, stream>>>(ecol, counts);
    scan_kernel<<<1, 1024, 0, stream>>>(counts, starts, cursor);
    dinv_kernel<<<(NNODES + 255) / 256, 256, 0, stream>>>(counts, dinv);
    scatter_kernel<<<(NEDGES + 255) / 256, 256, 0, stream>>>(erow, ecol, cursor, csr_row);
    encoder_mfma<<<(NNODES + 63) / 64, 256, 0, stream>>>(x, wencT, b_enc, h);
    aggregate_csr_kernel<<<(NNODES * 64 + 255) / 256, 256, 0, stream>>>(starts, csr_row, dinv, h, agg);
    decoder_mfma<<<(NNODES + 31) / 32, 256, 0, stream>>>(agg, gcn_bias, wdecT, b_dec, out);
}

// Round 4
// 285.381 us; speedup vs baseline: 2.1164x; 1.4496x over previous
//
#include <hip/hip_runtime.h>
#include <math.h>

#define NNODES 50000
#define NEDGES 640000
#define INSZ 512
#define HID 128
#define NBLK ((NNODES + 255) / 256)   // 196

typedef short s16x8 __attribute__((ext_vector_type(8)));
typedef float f32x4 __attribute__((ext_vector_type(4)));

static __device__ inline short f2bf(float f) {
    __bf16 b = (__bf16)f;
    return __builtin_bit_cast(short, b);
}

// ---------------- weight prep: transpose + bf16 convert ----------------
__global__ __launch_bounds__(256) void prep_wenc(const float* __restrict__ W,
                                                 short* __restrict__ WT) {
    int t = blockIdx.x * 256 + threadIdx.x;
    if (t < INSZ * HID) {
        int n = t & (HID - 1);
        int k = t >> 7;
        WT[n * INSZ + k] = f2bf(W[t]);
    }
}
__global__ __launch_bounds__(256) void prep_wdec(const float* __restrict__ W,
                                                 short* __restrict__ WT) {
    int t = blockIdx.x * 256 + threadIdx.x;
    if (t < HID * INSZ) {
        int n = t & (INSZ - 1);
        int k = t >> 9;
        WT[n * HID + k] = f2bf(W[t]);
    }
}

// ---------------- CSR build ----------------
__global__ __launch_bounds__(256) void count_kernel(const int* __restrict__ col,
                                                    int* __restrict__ counts) {
    int e = blockIdx.x * blockDim.x + threadIdx.x;
    if (e < NEDGES) atomicAdd(&counts[col[e]], 1);
}

// phase 1: per-block sums (coalesced, wave-reduced)
__global__ __launch_bounds__(256) void partial_kernel(const int* __restrict__ counts,
                                                      int* __restrict__ blocksums) {
    int i = blockIdx.x * 256 + threadIdx.x;
    int v = (i < NNODES) ? counts[i] : 0;
#pragma unroll
    for (int off = 32; off; off >>= 1) v += __shfl_down(v, off, 64);
    __shared__ int ws[4];
    if ((threadIdx.x & 63) == 0) ws[threadIdx.x >> 6] = v;
    __syncthreads();
    if (threadIdx.x == 0) blocksums[blockIdx.x] = ws[0] + ws[1] + ws[2] + ws[3];
}

// phase 2: scan 196 block sums (1 small block)
__global__ __launch_bounds__(256) void scan_blocks(const int* __restrict__ blocksums,
                                                   int* __restrict__ blockoffs) {
    __shared__ int s[256];
    const int t = threadIdx.x;
    s[t] = (t < NBLK) ? blocksums[t] : 0;
    __syncthreads();
    for (int off = 1; off < 256; off <<= 1) {
        int u = (t >= off) ? s[t - off] : 0;
        __syncthreads();
        s[t] += u;
        __syncthreads();
    }
    blockoffs[t] = (t == 0) ? 0 : s[t - 1];
}

// phase 3: block-local exclusive scan + offset; also computes dinv
__global__ __launch_bounds__(256) void scan_final(const int* __restrict__ counts,
                                                  const int* __restrict__ blockoffs,
                                                  int* __restrict__ starts,
                                                  int* __restrict__ cursor,
                                                  float* __restrict__ dinv) {
    __shared__ int s[256];
    const int t = threadIdx.x;
    const int i = blockIdx.x * 256 + t;
    int v = (i < NNODES) ? counts[i] : 0;
    s[t] = v;
    __syncthreads();
    for (int off = 1; off < 256; off <<= 1) {
        int u = (t >= off) ? s[t - off] : 0;
        __syncthreads();
        s[t] += u;
        __syncthreads();
    }
    int excl = ((t == 0) ? 0 : s[t - 1]) + blockoffs[blockIdx.x];
    if (i < NNODES) {
        starts[i] = excl;
        cursor[i] = excl;
        dinv[i] = rsqrtf((float)v + 1.0f);
        if (i == NNODES - 1) starts[NNODES] = excl + v;
    }
}

__global__ __launch_bounds__(256) void scatter_kernel(const int* __restrict__ erow,
                                                      const int* __restrict__ ecol,
                                                      int* __restrict__ cursor,
                                                      int* __restrict__ csr_row) {
    int e = blockIdx.x * blockDim.x + threadIdx.x;
    if (e < NEDGES) {
        int pos = atomicAdd(&cursor[ecol[e]], 1);
        csr_row[pos] = erow[e];
    }
}

// ---------------- encoder: h = relu(x @ W_enc + b_enc), MFMA bf16 ----------------
__global__ __launch_bounds__(256) void encoder_mfma(const float* __restrict__ x,
                                                    const short* __restrict__ WT,
                                                    const float* __restrict__ b,
                                                    float* __restrict__ h) {
    const int lane = threadIdx.x & 63;
    const int wv   = threadIdx.x >> 6;
    const int r16  = lane & 15;
    const int kg   = lane >> 4;
    const int mbase = blockIdx.x * 64;
    const int nb    = wv * 32;

    int arow[4];
#pragma unroll
    for (int mt = 0; mt < 4; ++mt) {
        int rr = mbase + mt * 16 + r16;
        arow[mt] = rr < NNODES ? rr : NNODES - 1;
    }

    f32x4 acc[4][2] = {};
    for (int ks = 0; ks < 16; ++ks) {
        const int k0 = ks * 32 + kg * 8;
        s16x8 a[4], bb[2];
#pragma unroll
        for (int mt = 0; mt < 4; ++mt) {
            const float* p = x + (size_t)arow[mt] * INSZ + k0;
            float4 u = *(const float4*)p;
            float4 v = *(const float4*)(p + 4);
            a[mt][0] = f2bf(u.x); a[mt][1] = f2bf(u.y);
            a[mt][2] = f2bf(u.z); a[mt][3] = f2bf(u.w);
            a[mt][4] = f2bf(v.x); a[mt][5] = f2bf(v.y);
            a[mt][6] = f2bf(v.z); a[mt][7] = f2bf(v.w);
        }
#pragma unroll
        for (int nt = 0; nt < 2; ++nt)
            bb[nt] = *(const s16x8*)(WT + (size_t)(nb + nt * 16 + r16) * INSZ + k0);
#pragma unroll
        for (int mt = 0; mt < 4; ++mt)
#pragma unroll
            for (int nt = 0; nt < 2; ++nt)
                acc[mt][nt] = __builtin_amdgcn_mfma_f32_16x16x32_bf16(a[mt], bb[nt], acc[mt][nt], 0, 0, 0);
    }

    const int ro = kg * 4;
#pragma unroll
    for (int mt = 0; mt < 4; ++mt) {
        const int row0 = mbase + mt * 16 + ro;
#pragma unroll
        for (int nt = 0; nt < 2; ++nt) {
            const int col = nb + nt * 16 + r16;
            const float bj = b[col];
#pragma unroll
            for (int v = 0; v < 4; ++v) {
                int rr = row0 + v;
                if (rr < NNODES)
                    h[(size_t)rr * HID + col] = fmaxf(acc[mt][nt][v] + bj, 0.0f);
            }
        }
    }
}

// ---------------- aggregation (CSR gather): one wave per target node, 4-way ILP ----
__global__ __launch_bounds__(256) void aggregate_csr_kernel(const int* __restrict__ starts,
                                                            const int* __restrict__ csr_row,
                                                            const float* __restrict__ dinv,
                                                            const float* __restrict__ h,
                                                            float* __restrict__ agg) {
    const int wid  = (blockIdx.x * 256 + threadIdx.x) >> 6;
    const int lane = threadIdx.x & 63;
    if (wid >= NNODES) return;
    const int c = wid;
    const float dc = dinv[c];
    const int s0 = starts[c], s1 = starts[c + 1];
    const float2* hp = (const float2*)h;

    float2 acc = hp[(size_t)c * 64 + lane];
    acc.x *= dc * dc;
    acc.y *= dc * dc;

    int i = s0;
    for (; i + 3 < s1; i += 4) {
        int r0 = csr_row[i], r1 = csr_row[i + 1], r2 = csr_row[i + 2], r3 = csr_row[i + 3];
        float n0 = dinv[r0] * dc, n1 = dinv[r1] * dc, n2 = dinv[r2] * dc, n3 = dinv[r3] * dc;
        float2 h0 = hp[(size_t)r0 * 64 + lane];
        float2 h1 = hp[(size_t)r1 * 64 + lane];
        float2 h2 = hp[(size_t)r2 * 64 + lane];
        float2 h3 = hp[(size_t)r3 * 64 + lane];
        acc.x = fmaf(n0, h0.x, acc.x); acc.y = fmaf(n0, h0.y, acc.y);
        acc.x = fmaf(n1, h1.x, acc.x); acc.y = fmaf(n1, h1.y, acc.y);
        acc.x = fmaf(n2, h2.x, acc.x); acc.y = fmaf(n2, h2.y, acc.y);
        acc.x = fmaf(n3, h3.x, acc.x); acc.y = fmaf(n3, h3.y, acc.y);
    }
    for (; i < s1; ++i) {
        int r = csr_row[i];
        float nrm = dinv[r] * dc;
        float2 hv = hp[(size_t)r * 64 + lane];
        acc.x = fmaf(nrm, hv.x, acc.x);
        acc.y = fmaf(nrm, hv.y, acc.y);
    }
    ((float2*)agg)[(size_t)c * 64 + lane] = acc;
}

// ---------------- decoder: out = sigmoid((agg+gb) @ W_dec + b_dec), MFMA bf16 -------
__global__ __launch_bounds__(256) void decoder_mfma(const float* __restrict__ agg,
                                                    const float* __restrict__ gb,
                                                    const short* __restrict__ WT,
                                                    const float* __restrict__ b,
                                                    float* __restrict__ out) {
    const int lane = threadIdx.x & 63;
    const int wv   = threadIdx.x >> 6;
    const int r16  = lane & 15;
    const int kg   = lane >> 4;
    const int mbase = blockIdx.x * 32;
    const int nb    = wv * 128;

    int arow[2];
#pragma unroll
    for (int mt = 0; mt < 2; ++mt) {
        int rr = mbase + mt * 16 + r16;
        arow[mt] = rr < NNODES ? rr : NNODES - 1;
    }

    f32x4 acc[2][8] = {};
#pragma unroll
    for (int ks = 0; ks < 4; ++ks) {
        const int k0 = ks * 32 + kg * 8;
        const float4 g0 = *(const float4*)(gb + k0);
        const float4 g1 = *(const float4*)(gb + k0 + 4);
        s16x8 a[2], bb[8];
#pragma unroll
        for (int mt = 0; mt < 2; ++mt) {
            const float* p = agg + (size_t)arow[mt] * HID + k0;
            float4 u = *(const float4*)p;
            float4 v = *(const float4*)(p + 4);
            a[mt][0] = f2bf(u.x + g0.x); a[mt][1] = f2bf(u.y + g0.y);
            a[mt][2] = f2bf(u.z + g0.z); a[mt][3] = f2bf(u.w + g0.w);
            a[mt][4] = f2bf(v.x + g1.x); a[mt][5] = f2bf(v.y + g1.y);
            a[mt][6] = f2bf(v.z + g1.z); a[mt][7] = f2bf(v.w + g1.w);
        }
#pragma unroll
        for (int nt = 0; nt < 8; ++nt)
            bb[nt] = *(const s16x8*)(WT + (size_t)(nb + nt * 16 + r16) * HID + k0);
#pragma unroll
        for (int mt = 0; mt < 2; ++mt)
#pragma unroll
            for (int nt = 0; nt < 8; ++nt)
                acc[mt][nt] = __builtin_amdgcn_mfma_f32_16x16x32_bf16(a[mt], bb[nt], acc[mt][nt], 0, 0, 0);
    }

    const int ro = kg * 4;
#pragma unroll
    for (int mt = 0; mt < 2; ++mt) {
        const int row0 = mbase + mt * 16 + ro;
#pragma unroll
        for (int nt = 0; nt < 8; ++nt) {
            const int col = nb + nt * 16 + r16;
            const float bj = b[col];
#pragma unroll
            for (int v = 0; v < 4; ++v) {
                int rr = row0 + v;
                if (rr < NNODES) {
                    float z = acc[mt][nt][v] + bj;
                    out[(size_t)rr * INSZ + col] = 1.0f / (1.0f + __expf(-z));
                }
            }
        }
    }
}

extern "C" void kernel_launch(void* const* d_in, const int* in_sizes, int n_in,
                              void* d_out, int out_size, void* d_ws, size_t ws_size,
                              hipStream_t stream) {
    const float* x        = (const float*)d_in[0];
    const float* W_enc    = (const float*)d_in[1];
    const float* b_enc    = (const float*)d_in[2];
    const float* W_dec    = (const float*)d_in[3];
    const float* b_dec    = (const float*)d_in[4];
    const float* gcn_bias = (const float*)d_in[5];
    const int*   edge     = (const int*)d_in[6];
    const int*   erow = edge;
    const int*   ecol = edge + NEDGES;

    float* out = (float*)d_out;
    // ws: agg (6.4M f32) + dinv (50K f32) + W_decT (64K bf16)
    float* agg   = (float*)d_ws;
    float* dinv  = agg + (size_t)NNODES * HID;
    short* wdecT = (short*)(dinv + NNODES);
    // d_out tail scratch (all dead before decoder writes d_out):
    float* h         = out;
    int*   csr_row   = (int*)(out + (size_t)NNODES * HID);
    int*   starts    = csr_row + NEDGES;
    int*   counts    = starts + NNODES + 1;
    int*   cursor    = counts + NNODES;
    int*   blocksums = cursor + NNODES;
    int*   blockoffs = blocksums + 256;
    short* wencT     = (short*)(blockoffs + 256);

    hipMemsetAsync(counts, 0, (size_t)NNODES * sizeof(int), stream);
    prep_wenc<<<(INSZ * HID + 255) / 256, 256, 0, stream>>>(W_enc, wencT);
    prep_wdec<<<(HID * INSZ + 255) / 256, 256, 0, stream>>>(W_dec, wdecT);
    count_kernel<<<(NEDGES + 255) / 256, 256, 0, stream>>>(ecol, counts);
    partial_kernel<<<NBLK, 256, 0, stream>>>(counts, blocksums);
    scan_blocks<<<1, 256, 0, stream>>>(blocksums, blockoffs);
    scan_final<<<NBLK, 256, 0, stream>>>(counts, blockoffs, starts, cursor, dinv);
    scatter_kernel<<<(NEDGES + 255) / 256, 256, 0, stream>>>(erow, ecol, cursor, csr_row);
    encoder_mfma<<<(NNODES + 63) / 64, 256, 0, stream>>>(x, wencT, b_enc, h);
    aggregate_csr_kernel<<<(NNODES * 64 + 255) / 256, 256, 0, stream>>>(starts, csr_row, dinv, h, agg);
    decoder_mfma<<<(NNODES + 31) / 32, 256, 0, stream>>>(agg, gcn_bias, wdecT, b_dec, out);
}